// Round 2
// baseline (389.757 us; speedup 1.0000x reference)
//
#include <hip/hip_runtime.h>
#include <hip/hip_bf16.h>

// Fused QKV projection: qkv = hidden[16384,1024] @ Wqkv[1024,3072] + bias,
// scattered to q/k/v [4,16,4096,64] each, fp32 out.
// R2: XOR-swizzled LDS layout (k-quad slot p = kq ^ ((row>>1)&3)) kills the
// 8-way bank conflict on fragment ds_read_b128 (R1: 1.26e7 conflicts).
// Swizzle applied on the staging side by permuting each lane's global source
// (global_load_lds dest is fixed at base + lane*16).

#define M_TOT 16384
#define N_TOT 3072
#define K_TOT 1024

typedef __bf16 bf16x8 __attribute__((ext_vector_type(8)));
typedef float f32x4 __attribute__((ext_vector_type(4)));

#define AS1(p) ((const __attribute__((address_space(1))) void*)(p))
#define AS3(p) ((__attribute__((address_space(3))) void*)(p))

__device__ __forceinline__ unsigned short f2bf(float f) {
    unsigned int u = __builtin_bit_cast(unsigned int, f);
    u += 0x7fffu + ((u >> 16) & 1u);
    return (unsigned short)(u >> 16);
}

// ---- kernel 1: hidden fp32 -> bf16, straight copy (row-major [16384][1024])
__global__ void convert_hidden(const float* __restrict__ x,
                               unsigned short* __restrict__ y, int n4) {
    int i = blockIdx.x * blockDim.x + threadIdx.x;
    int stride = gridDim.x * blockDim.x;
    for (; i < n4; i += stride) {
        float4 v = ((const float4*)x)[i];
        ushort4 o;
        o.x = f2bf(v.x); o.y = f2bf(v.y); o.z = f2bf(v.z); o.w = f2bf(v.w);
        ((ushort4*)y)[i] = o;
    }
}

// ---- kernel 2: W[k][f] fp32 -> Bt[wsel*1024 + f][k] bf16 (transpose), tiled 64x64
__global__ void convert_weights(const float* __restrict__ Wq,
                                const float* __restrict__ Wk,
                                const float* __restrict__ Wv,
                                unsigned short* __restrict__ Bt) {
    __shared__ unsigned short tile[64][65];
    const float* W = (blockIdx.z == 0) ? Wq : (blockIdx.z == 1) ? Wk : Wv;
    int k0 = blockIdx.y * 64;
    int f0 = blockIdx.x * 64;
    int tx = threadIdx.x & 63;
    int ty = threadIdx.x >> 6;  // 0..3
#pragma unroll
    for (int r = 0; r < 16; ++r) {
        int k = ty + r * 4;
        tile[k][tx] = f2bf(W[(size_t)(k0 + k) * 1024 + f0 + tx]);
    }
    __syncthreads();
#pragma unroll
    for (int r = 0; r < 16; ++r) {
        int fr = ty + r * 4;
        Bt[(size_t)(blockIdx.z * 1024 + f0 + fr) * 1024 + k0 + tx] = tile[tx][fr];
    }
}

// ---- kernel 3: GEMM + bias + scatter-to-heads epilogue
// A  [16384][1024] bf16 row-major, Bt [3072][1024] bf16 (W^T), out fp32.
// Block 256 thr = 4 waves; tile BM=128 BN=128 BK=32; wave -> 64x64 via 4x4
// mfma_f32_16x16x32_bf16. Staging via global_load_lds width=16.
// LDS swizzle: row r's logical k-quad kq lives at slot p = kq ^ ((r>>1)&3).
__launch_bounds__(256, 2)
__global__ void qkv_gemm(const unsigned short* __restrict__ A,
                         const unsigned short* __restrict__ Bt,
                         const float* __restrict__ bq,
                         const float* __restrict__ bk,
                         const float* __restrict__ bv,
                         float* __restrict__ out) {
    __shared__ __align__(16) unsigned short As[128 * 32];  // row stride 32 ush = 64 B
    __shared__ __align__(16) unsigned short Bs[128 * 32];

    const int tid  = threadIdx.x;
    const int wave = tid >> 6;
    const int lane = tid & 63;
    const int quad = lane >> 4;
    const int l16  = lane & 15;

    const int bm = blockIdx.x;  // 0..127 (M tiles)
    const int bn = blockIdx.y;  // 0..23  (N tiles)

    const int wr = wave >> 1;   // 0..1
    const int wc = wave & 1;    // 0..1

    f32x4 acc[4][4] = {};

    // staging: LDS chunk c = issue*256 + wave*64 + lane; row = c>>2, slot p = c&3.
    // slot p holds logical k-quad kq = p ^ ((row>>1)&3)  -> lane fetches that kq.
    const int c0 = wave * 64 + lane;
    const int rowA0 = c0 >> 2;
    const int k8A0  = ((c0 & 3) ^ ((rowA0 >> 1) & 3)) * 8;
    const int c1 = 256 + c0;
    const int rowA1 = c1 >> 2;
    const int k8A1  = ((c1 & 3) ^ ((rowA1 >> 1) & 3)) * 8;

    const unsigned short* gA0 = A  + (size_t)(bm * 128 + rowA0) * 1024 + k8A0;
    const unsigned short* gA1 = A  + (size_t)(bm * 128 + rowA1) * 1024 + k8A1;
    const unsigned short* gB0 = Bt + (size_t)(bn * 128 + rowA0) * 1024 + k8A0;
    const unsigned short* gB1 = Bt + (size_t)(bn * 128 + rowA1) * 1024 + k8A1;

    unsigned short* ldsA0 = As + (size_t)(wave)*512;
    unsigned short* ldsA1 = As + (size_t)(4 + wave) * 512;
    unsigned short* ldsB0 = Bs + (size_t)(wave)*512;
    unsigned short* ldsB1 = Bs + (size_t)(4 + wave) * 512;

    // read-side swizzled slot: for fragment row = base16 + l16 (base16 % 16 == 0),
    // ((row>>1)&3) == ((l16>>1)&3)  -> lane-constant across all i/j.
    const int sw8 = ((quad ^ ((l16 >> 1) & 3)) * 8);

    for (int k0 = 0; k0 < K_TOT; k0 += 32) {
        __builtin_amdgcn_global_load_lds(AS1(gA0 + k0), AS3(ldsA0), 16, 0, 0);
        __builtin_amdgcn_global_load_lds(AS1(gA1 + k0), AS3(ldsA1), 16, 0, 0);
        __builtin_amdgcn_global_load_lds(AS1(gB0 + k0), AS3(ldsB0), 16, 0, 0);
        __builtin_amdgcn_global_load_lds(AS1(gB1 + k0), AS3(ldsB1), 16, 0, 0);
        __syncthreads();

        bf16x8 av[4], bvf[4];
#pragma unroll
        for (int i = 0; i < 4; ++i) {
            int arow = wr * 64 + i * 16 + l16;
            av[i] = *(const bf16x8*)&As[arow * 32 + sw8];
        }
#pragma unroll
        for (int j = 0; j < 4; ++j) {
            int brow = wc * 64 + j * 16 + l16;
            bvf[j] = *(const bf16x8*)&Bs[brow * 32 + sw8];
        }
#pragma unroll
        for (int i = 0; i < 4; ++i)
#pragma unroll
            for (int j = 0; j < 4; ++j)
                acc[i][j] = __builtin_amdgcn_mfma_f32_16x16x32_bf16(av[i], bvf[j], acc[i][j], 0, 0, 0);
        __syncthreads();
    }

    // Epilogue: C/D frag mapping col = lane&15, row = quad*4 + reg.
    const int section = (bn * 128) >> 10;                       // 0,1,2
    const int nloc0   = (bn * 128 - section * 1024) + wc * 64;  // col within section
    const float* bias = (section == 0) ? bq : (section == 1) ? bk : bv;
    float* outsec = out + (size_t)section * (4u * 16u * 4096u * 64u);

#pragma unroll
    for (int j = 0; j < 4; ++j) {
        int f = nloc0 + j * 16 + l16;  // 0..1023 within section
        float bval = bias[f];
        int h = f >> 6, d = f & 63;
        size_t hb = (size_t)h * (4096u * 64u);
#pragma unroll
        for (int i = 0; i < 4; ++i) {
            int mbase = bm * 128 + wr * 64 + i * 16 + quad * 4;
#pragma unroll
            for (int r = 0; r < 4; ++r) {
                int m = mbase + r;
                int b = m >> 12, s = m & 4095;
                outsec[(size_t)b * (16u * 4096u * 64u) + hb + (size_t)s * 64u + d] =
                    acc[i][j][r] + bval;
            }
        }
    }
}

extern "C" void kernel_launch(void* const* d_in, const int* in_sizes, int n_in,
                              void* d_out, int out_size, void* d_ws, size_t ws_size,
                              hipStream_t stream) {
    const float* hs = (const float*)d_in[0];
    const float* Wq = (const float*)d_in[1];
    const float* bq = (const float*)d_in[2];
    const float* Wk = (const float*)d_in[3];
    const float* bk = (const float*)d_in[4];
    const float* Wv = (const float*)d_in[5];
    const float* bv = (const float*)d_in[6];
    float* out = (float*)d_out;

    unsigned short* Abf  = (unsigned short*)d_ws;            // 16384*1024 bf16 = 32 MiB
    unsigned short* Btbf = Abf + (size_t)M_TOT * K_TOT;      // 3072*1024  bf16 =  6 MiB

    convert_hidden<<<2048, 256, 0, stream>>>(hs, Abf, (M_TOT * K_TOT) / 4);
    convert_weights<<<dim3(16, 16, 3), 256, 0, stream>>>(Wq, Wk, Wv, Btbf);
    qkv_gemm<<<dim3(M_TOT / 128, N_TOT / 128), 256, 0, stream>>>(Abf, Btbf, bq, bk, bv, out);
}

// Round 3
// 371.603 us; speedup vs baseline: 1.0489x; 1.0489x over previous
//
#include <hip/hip_runtime.h>
#include <hip/hip_bf16.h>

// Fused QKV projection: qkv = hidden[16384,1024] @ Wqkv[1024,3072] + bias,
// scattered to q/k/v [4,16,4096,64] each, fp32 out.
// R3: switch MFMA 16x16x32 (4x4) -> 32x32x16 (2x2). Same LDS traffic and
// fragment width (16 B), ~17% fewer MFMA issue cycles, higher ubench ceiling.
// Keeps R2's zero-conflict XOR swizzle (slot p = kq ^ ((row>>1)&3)) applied
// on the staging side by permuting each lane's global source pointer.

#define M_TOT 16384
#define N_TOT 3072
#define K_TOT 1024

typedef __bf16 bf16x8 __attribute__((ext_vector_type(8)));
typedef float f32x16 __attribute__((ext_vector_type(16)));

#define AS1(p) ((const __attribute__((address_space(1))) void*)(p))
#define AS3(p) ((__attribute__((address_space(3))) void*)(p))

__device__ __forceinline__ unsigned short f2bf(float f) {
    unsigned int u = __builtin_bit_cast(unsigned int, f);
    u += 0x7fffu + ((u >> 16) & 1u);
    return (unsigned short)(u >> 16);
}

// ---- kernel 1: hidden fp32 -> bf16, straight copy (row-major [16384][1024])
__global__ void convert_hidden(const float* __restrict__ x,
                               unsigned short* __restrict__ y, int n4) {
    int i = blockIdx.x * blockDim.x + threadIdx.x;
    int stride = gridDim.x * blockDim.x;
    for (; i < n4; i += stride) {
        float4 v = ((const float4*)x)[i];
        ushort4 o;
        o.x = f2bf(v.x); o.y = f2bf(v.y); o.z = f2bf(v.z); o.w = f2bf(v.w);
        ((ushort4*)y)[i] = o;
    }
}

// ---- kernel 2: W[k][f] fp32 -> Bt[wsel*1024 + f][k] bf16 (transpose), tiled 64x64
__global__ void convert_weights(const float* __restrict__ Wq,
                                const float* __restrict__ Wk,
                                const float* __restrict__ Wv,
                                unsigned short* __restrict__ Bt) {
    __shared__ unsigned short tile[64][65];
    const float* W = (blockIdx.z == 0) ? Wq : (blockIdx.z == 1) ? Wk : Wv;
    int k0 = blockIdx.y * 64;
    int f0 = blockIdx.x * 64;
    int tx = threadIdx.x & 63;
    int ty = threadIdx.x >> 6;  // 0..3
#pragma unroll
    for (int r = 0; r < 16; ++r) {
        int k = ty + r * 4;
        tile[k][tx] = f2bf(W[(size_t)(k0 + k) * 1024 + f0 + tx]);
    }
    __syncthreads();
#pragma unroll
    for (int r = 0; r < 16; ++r) {
        int fr = ty + r * 4;
        Bt[(size_t)(blockIdx.z * 1024 + f0 + fr) * 1024 + k0 + tx] = tile[tx][fr];
    }
}

// ---- kernel 3: GEMM + bias + scatter-to-heads epilogue
// A  [16384][1024] bf16 row-major, Bt [3072][1024] bf16 (W^T), out fp32.
// Block 256 thr = 4 waves; tile BM=128 BN=128 BK=32; wave -> 64x64 via 2x2
// mfma_f32_32x32x16_bf16 (2 k-steps of 16 per BK=32 iter).
// Staging via global_load_lds width=16; LDS row stride 64 B; swizzle:
// row r's logical k-octet kq lives at slot p = kq ^ ((r>>1)&3).
__launch_bounds__(256, 2)
__global__ void qkv_gemm(const unsigned short* __restrict__ A,
                         const unsigned short* __restrict__ Bt,
                         const float* __restrict__ bq,
                         const float* __restrict__ bk,
                         const float* __restrict__ bv,
                         float* __restrict__ out) {
    __shared__ __align__(16) unsigned short As[128 * 32];  // row stride 32 ush = 64 B
    __shared__ __align__(16) unsigned short Bs[128 * 32];

    const int tid  = threadIdx.x;
    const int wave = tid >> 6;
    const int lane = tid & 63;
    const int r5   = lane & 31;   // row within a 32-row MFMA block
    const int half = lane >> 5;   // selects k-octet within a k-step

    const int bm = blockIdx.x;  // 0..127 (M tiles)
    const int bn = blockIdx.y;  // 0..23  (N tiles)

    const int wr = wave >> 1;   // 0..1
    const int wc = wave & 1;    // 0..1

    f32x16 acc[2][2] = {};

    // staging: LDS chunk c = issue*256 + wave*64 + lane; row = c>>2, slot p = c&3.
    // slot p holds logical k-octet kq = p ^ ((row>>1)&3) -> lane fetches that kq.
    const int c0 = wave * 64 + lane;
    const int rowA0 = c0 >> 2;
    const int k8A0  = ((c0 & 3) ^ ((rowA0 >> 1) & 3)) * 8;
    const int c1 = 256 + c0;
    const int rowA1 = c1 >> 2;
    const int k8A1  = ((c1 & 3) ^ ((rowA1 >> 1) & 3)) * 8;

    const unsigned short* gA0 = A  + (size_t)(bm * 128 + rowA0) * 1024 + k8A0;
    const unsigned short* gA1 = A  + (size_t)(bm * 128 + rowA1) * 1024 + k8A1;
    const unsigned short* gB0 = Bt + (size_t)(bn * 128 + rowA0) * 1024 + k8A0;
    const unsigned short* gB1 = Bt + (size_t)(bn * 128 + rowA1) * 1024 + k8A1;

    unsigned short* ldsA0 = As + (size_t)(wave)*512;
    unsigned short* ldsA1 = As + (size_t)(4 + wave) * 512;
    unsigned short* ldsB0 = Bs + (size_t)(wave)*512;
    unsigned short* ldsB1 = Bs + (size_t)(4 + wave) * 512;

    // read-side: fragment row = base32 + r5 (base32 % 32 == 0), so
    // (row>>1)&3 == (r5>>1)&3 -> lane-constant across all blocks/k-steps.
    const int swsel = (r5 >> 1) & 3;

    for (int k0 = 0; k0 < K_TOT; k0 += 32) {
        __builtin_amdgcn_global_load_lds(AS1(gA0 + k0), AS3(ldsA0), 16, 0, 0);
        __builtin_amdgcn_global_load_lds(AS1(gA1 + k0), AS3(ldsA1), 16, 0, 0);
        __builtin_amdgcn_global_load_lds(AS1(gB0 + k0), AS3(ldsB0), 16, 0, 0);
        __builtin_amdgcn_global_load_lds(AS1(gB1 + k0), AS3(ldsB1), 16, 0, 0);
        __syncthreads();

        // A-frag (32x32x16): m = r5, k = half*8 + j  -> octet o = ks*2 + half
        bf16x8 av[2][2], bvv[2][2];  // [block][kstep]
#pragma unroll
        for (int ib = 0; ib < 2; ++ib) {
            int arow = wr * 64 + ib * 32 + r5;
#pragma unroll
            for (int ks = 0; ks < 2; ++ks) {
                int p = (ks * 2 + half) ^ swsel;
                av[ib][ks] = *(const bf16x8*)&As[arow * 32 + p * 8];
            }
        }
#pragma unroll
        for (int jb = 0; jb < 2; ++jb) {
            int brow = wc * 64 + jb * 32 + r5;
#pragma unroll
            for (int ks = 0; ks < 2; ++ks) {
                int p = (ks * 2 + half) ^ swsel;
                bvv[jb][ks] = *(const bf16x8*)&Bs[brow * 32 + p * 8];
            }
        }
#pragma unroll
        for (int ks = 0; ks < 2; ++ks)
#pragma unroll
            for (int ib = 0; ib < 2; ++ib)
#pragma unroll
                for (int jb = 0; jb < 2; ++jb)
                    acc[ib][jb] = __builtin_amdgcn_mfma_f32_32x32x16_bf16(
                        av[ib][ks], bvv[jb][ks], acc[ib][jb], 0, 0, 0);
        __syncthreads();
    }

    // Epilogue: 32x32 C/D mapping col = lane&31, row = (reg&3)+8*(reg>>2)+4*half.
    const int section = (bn * 128) >> 10;                       // 0,1,2
    const int nloc0   = (bn * 128 - section * 1024) + wc * 64;  // col within section
    const float* bias = (section == 0) ? bq : (section == 1) ? bk : bv;
    float* outsec = out + (size_t)section * (4u * 16u * 4096u * 64u);

#pragma unroll
    for (int jb = 0; jb < 2; ++jb) {
        int f = nloc0 + jb * 32 + r5;  // 0..1023 within section
        float bval = bias[f];
        int h = f >> 6, d = f & 63;
        size_t hb = (size_t)h * (4096u * 64u);
#pragma unroll
        for (int ib = 0; ib < 2; ++ib) {
            int mbase = bm * 128 + wr * 64 + ib * 32 + 4 * half;
#pragma unroll
            for (int reg = 0; reg < 16; ++reg) {
                int m = mbase + (reg & 3) + 8 * (reg >> 2);
                int b = m >> 12, s = m & 4095;
                outsec[(size_t)b * (16u * 4096u * 64u) + hb + (size_t)s * 64u + d] =
                    acc[ib][jb][reg] + bval;
            }
        }
    }
}

extern "C" void kernel_launch(void* const* d_in, const int* in_sizes, int n_in,
                              void* d_out, int out_size, void* d_ws, size_t ws_size,
                              hipStream_t stream) {
    const float* hs = (const float*)d_in[0];
    const float* Wq = (const float*)d_in[1];
    const float* bq = (const float*)d_in[2];
    const float* Wk = (const float*)d_in[3];
    const float* bk = (const float*)d_in[4];
    const float* Wv = (const float*)d_in[5];
    const float* bv = (const float*)d_in[6];
    float* out = (float*)d_out;

    unsigned short* Abf  = (unsigned short*)d_ws;            // 16384*1024 bf16 = 32 MiB
    unsigned short* Btbf = Abf + (size_t)M_TOT * K_TOT;      // 3072*1024  bf16 =  6 MiB

    convert_hidden<<<2048, 256, 0, stream>>>(hs, Abf, (M_TOT * K_TOT) / 4);
    convert_weights<<<dim3(16, 16, 3), 256, 0, stream>>>(Wq, Wk, Wv, Btbf);
    qkv_gemm<<<dim3(M_TOT / 128, N_TOT / 128), 256, 0, stream>>>(Abf, Btbf, bq, bk, bv, out);
}